// Round 16
// baseline (326.971 us; speedup 1.0000x reference)
//
#include <hip/hip_runtime.h>
#include <hip/hip_bf16.h>

#define HIDDEN   2880
#define INTER    2880
#define NEXP     8
#define GUP_ROWS 5760
#define NPAIR    2048

#define BM    320
#define PLANE_B 5120         // one 8-k plane: 320 rows x 16B
#define KT64_B  40960        // BK=64 tile: 8 planes
#define NKT64   45
#define KT32_B  20480        // BK=32 tile: 4 planes
#define NKT32   90

#define MAXTILES 15
#define IMG_BYTES ((size_t)MAXTILES * NKT64 * KT64_B)

using bf16x8 = __attribute__((ext_vector_type(8))) short;
using f32x4  = __attribute__((ext_vector_type(4))) float;

typedef const __attribute__((address_space(1))) unsigned GBuf;
typedef __attribute__((address_space(3))) unsigned LBuf;

__device__ __forceinline__ void gl2lds(const void* g, void* l) {
  __builtin_amdgcn_global_load_lds((GBuf*)g, (LBuf*)l, 16, 0, 0);
}
#define WAITVM(N) { asm volatile("s_waitcnt vmcnt(" #N ")" ::: "memory"); \
                    __builtin_amdgcn_sched_barrier(0); }
#define WAITLGKM0 { asm volatile("s_waitcnt lgkmcnt(0)" ::: "memory"); \
                    __builtin_amdgcn_sched_barrier(0); }
__device__ __forceinline__ void barrier() {
  __builtin_amdgcn_sched_barrier(0);
  __builtin_amdgcn_s_barrier();
  __builtin_amdgcn_sched_barrier(0);
}

__device__ __forceinline__ unsigned cvt2bf(float a, float b) {
  union { __hip_bfloat16 h; unsigned short s; } x, y;
  x.h = __float2bfloat16(a);
  y.h = __float2bfloat16(b);
  return (unsigned)x.s | ((unsigned)y.s << 16);
}

// ---------------- routing ----------------
__global__ void route_count(const int* __restrict__ eidx, int* __restrict__ meta) {
  __shared__ int cnt[NEXP];
  int t = threadIdx.x;
  if (t < NEXP) cnt[t] = 0;
  __syncthreads();
  for (int a = t; a < NPAIR; a += 256) atomicAdd(&cnt[eidx[a]], 1);
  __syncthreads();
  if (t == 0) {
    int off = 0, toff = 0;
    for (int e = 0; e < NEXP; ++e) {
      meta[e] = cnt[e];
      meta[8 + e] = off;
      meta[16 + e] = off;
      meta[24 + e] = toff;
      off += cnt[e];
      toff += (cnt[e] + BM - 1) / BM;
    }
  }
}

__global__ void route_scatter(const int* __restrict__ eidx, int* __restrict__ meta,
                              int* __restrict__ list) {
  int a = blockIdx.x * 256 + threadIdx.x;
  int e = eidx[a];
  int pos = atomicAdd(&meta[16 + e], 1);
  list[pos] = a;
}

// ---------------- gather A rows -> bf16 tiled fragment image ----------------
// layout: [tile][k>>3 plane 0..359][row 0..319][16B]
__global__ void gather_a(const float* __restrict__ t, const int* __restrict__ eidx,
                         const int* __restrict__ meta, const int* __restrict__ list,
                         char* __restrict__ atile) {
  const int i = blockIdx.x;
  const int a = list[i];
  const int e = eidx[a];
  const int r = i - meta[8 + e];
  const int tile = meta[24 + e] + r / BM;
  const int row = r % BM;
  const float* src = t + (size_t)(a >> 2) * HIDDEN;
  for (int ch = threadIdx.x; ch < HIDDEN / 8; ch += 256) {
    const float4* s = (const float4*)(src + ch * 8);
    float4 v0 = s[0], v1 = s[1];
    uint4 w;
    w.x = cvt2bf(v0.x, v0.y); w.y = cvt2bf(v0.z, v0.w);
    w.z = cvt2bf(v1.x, v1.y); w.w = cvt2bf(v1.z, v1.w);
    *(uint4*)(atile + ((size_t)tile * 360 + ch) * PLANE_B + row * 16) = w;
  }
}

// ---------------- GEMM1: 4 waves, tile 320x64, BK=32, 48KB LDS -> 3 blocks/CU ----------------
// A via gl2lds (V-skip); B reg-staged f32->bf16, k-plane-major LDS (conflict-free reads).
// Per-wave vmem per iter: 2 B-loads then V A-glds -> WAITVM(V+2).
#define B1BASE 40960
__global__ __launch_bounds__(256, 3)
void gemm1_swiglu(const char* __restrict__ aimg,
                  const float* __restrict__ gup,
                  const float* __restrict__ gub,
                  const int* __restrict__ meta,
                  char* __restrict__ uimg)
{
  const int e = blockIdx.x, nt = blockIdx.y, mt = blockIdx.z;
  const int n_e = meta[e];
  const int m0 = mt * BM;
  if (m0 >= n_e) return;
  const int tile = meta[24 + e] + mt;
  int rows = n_e - m0; if (rows > BM) rows = BM;
  int V = (rows + 63) >> 6; if (V < 4) V = 4;   // 4 or 5, block-uniform

  __shared__ __align__(16) char lds[49152];   // A 2x20KB + B 2x4KB

  const int tid = threadIdx.x, lane = tid & 63, wid = tid >> 6;
  const int wm = wid;
  const int kq = lane >> 4, l15 = lane & 15;

  const char* aSrc = aimg + (size_t)tile * 360 * PLANE_B;
  // A: 20 chunks of 1KB; wave w owns plane w's 5 row-groups (c = 5w+j -> plane=w, group=j)
  const char* srcA[5]; int dstA[5];
  #pragma unroll
  for (int j = 0; j < 5; ++j) {
    int c = wid * 5 + j;
    srcA[j] = aSrc + c * 1024 + lane * 16;
    dstA[j] = c * 1024;
  }
  // B: thread t loads 8 f32 of col c = t>>2, k-seg = t&3 (8 k each)
  const int bcol = tid >> 2, bseg = tid & 3;
  const float* bSrc = gup + (size_t)(e * GUP_ROWS + nt * 64 + bcol) * HIDDEN + bseg * 8;
  const int bDst = bseg * 1024 + bcol * 16;   // k-plane-major: [kq 0..3][col 0..63][16B]

  float4 rb0, rb1;
  auto LOADB = [&](int kt) {
    rb0 = *(const float4*)(bSrc + (size_t)kt * 32);
    rb1 = *(const float4*)(bSrc + (size_t)kt * 32 + 4);
  };
  auto STAGEA = [&](int kt, int buf) {
    char* dst = lds + buf * 20480;
    #pragma unroll
    for (int j = 0; j < 5; ++j)
      if (j < V)
        gl2lds(srcA[j] + (size_t)kt * KT32_B, dst + dstA[j]);
  };
  auto WRITEB = [&](int buf) {
    uint4 w;
    w.x = cvt2bf(rb0.x, rb0.y); w.y = cvt2bf(rb0.z, rb0.w);
    w.z = cvt2bf(rb1.x, rb1.y); w.w = cvt2bf(rb1.z, rb1.w);
    *(uint4*)(lds + B1BASE + buf * 4096 + bDst) = w;
    WAITLGKM0
  };

  f32x4 acc[5][4];
  #pragma unroll
  for (int fm = 0; fm < 5; ++fm)
    #pragma unroll
    for (int fn = 0; fn < 4; ++fn)
      acc[fm][fn] = f32x4{0.f, 0.f, 0.f, 0.f};

  auto COMP = [&](int buf) {
    const char* aB = lds + buf * 20480 + kq * PLANE_B + (wm * 80 + l15) * 16;
    const char* bB = lds + B1BASE + buf * 4096 + kq * 1024;
    bf16x8 af[5], bf[4];
    #pragma unroll
    for (int fm = 0; fm < 5; ++fm) af[fm] = *(const bf16x8*)(aB + fm * 256);
    #pragma unroll
    for (int fn = 0; fn < 4; ++fn) bf[fn] = *(const bf16x8*)(bB + (fn * 16 + l15) * 16);
    #pragma unroll
    for (int fm = 0; fm < 5; ++fm)
      #pragma unroll
      for (int fn = 0; fn < 4; ++fn)
        acc[fm][fn] = __builtin_amdgcn_mfma_f32_16x16x32_bf16(af[fm], bf[fn], acc[fm][fn], 0, 0, 0);
  };

  LOADB(0);
  STAGEA(0, 0);
  WRITEB(0);                       // compiler waits vmcnt(V) -> B0 done, A0 in flight
  for (int kt = 0; kt < NKT32; ++kt) {
    if (kt + 1 < NKT32) {
      LOADB(kt + 1);
      STAGEA(kt + 1, (kt + 1) & 1);
      if (V == 5) { WAITVM(7) } else { WAITVM(6) }   // prev A done
    } else { WAITVM(0) }
    barrier();
    COMP(kt & 1);
    if (kt + 1 < NKT32) WRITEB((kt + 1) & 1);        // waits B regs only; A stays in flight
    barrier();
  }

  // epilogue: +bias, swiglu (even col = glu, odd = lin), write u into uimg
  #pragma unroll
  for (int fm = 0; fm < 5; ++fm) {
    #pragma unroll
    for (int fn = 0; fn < 4; ++fn) {
      const int colg = nt * 64 + fn * 16 + l15;
      const float bias = gub[e * GUP_ROWS + colg];
      #pragma unroll
      for (int j = 0; j < 4; ++j) {
        float h = acc[fm][fn][j] + bias;
        float other = __shfl_xor(h, 1, 64);
        int rowin = wm * 80 + fm * 16 + kq * 4 + j;
        if (!(lane & 1) && rowin < rows) {
          float xg = fminf(h, 7.0f);
          float xl = fminf(fmaxf(other, -7.0f), 7.0f);
          float og = xg / (1.0f + __expf(-1.702f * xg));
          float uv = og * (xl + 1.0f);
          int uc = colg >> 1;                      // 0..2879
          *(__hip_bfloat16*)(uimg + ((size_t)tile * 360 + (uc >> 3)) * PLANE_B +
              rowin * 16 + (uc & 7) * 2) = __float2bfloat16(uv);
        }
      }
    }
  }
}

// ---------------- GEMM2: 8 waves (4 wm x 2 wn), tile 320x96, BK=64, V-skip (R15 proven) ----------------
__global__ __launch_bounds__(512, 1)
void gemm2_down(const char* __restrict__ uimg,
                const float* __restrict__ dwn,
                const float* __restrict__ dbias,
                const int* __restrict__ meta,
                const int* __restrict__ list,
                float* __restrict__ out)
{
  constexpr int BN_ = 96;
  constexpr int BBUF = BN_ * 256;       // 24576

  const int e = blockIdx.x, nt = blockIdx.y, mt = blockIdx.z;
  const int n_e = meta[e];
  const int m0 = mt * BM;
  if (m0 >= n_e) return;
  const int tile = meta[24 + e] + mt;
  int rows = n_e - m0; if (rows > BM) rows = BM;
  int V = (rows + 63) >> 6; if (V < 4) V = 4;   // 4 or 5

  __shared__ __align__(16) char lds[2 * KT64_B + 2 * BBUF];   // 128 KB
  char* ldsB = lds + 2 * KT64_B;

  const int tid = threadIdx.x, lane = tid & 63, wid = tid >> 6;
  const int wm = wid >> 1, wn = wid & 1;
  const int kq = lane >> 4, l15 = lane & 15;

  const char* aSrcBase = uimg + (size_t)tile * 360 * PLANE_B;
  const char* srcA[5]; int dstA[5];
  #pragma unroll
  for (int j = 0; j < 5; ++j) {
    srcA[j] = aSrcBase + wid * PLANE_B + j * 1024 + lane * 16;
    dstA[j] = wid * PLANE_B + j * 1024;
  }
  const char* srcB[3]; int dstB[3];
  #pragma unroll
  for (int j = 0; j < 3; ++j) {
    int cb = wid * 3 + j;
    int col = nt * BN_ + cb * 4 + (lane >> 4);
    int s16 = lane & 15;
    int swz = (((s16 >> 1) ^ (col & 7)) << 5) | ((s16 & 1) << 4);
    srcB[j] = (const char*)dwn + ((size_t)(e * HIDDEN + col) * INTER) * 4 + swz;
    dstB[j] = cb * 1024;
  }

  auto STAGE = [&](int kt, int buf) {
    #pragma unroll
    for (int j = 0; j < 5; ++j)
      if (j < V)
        gl2lds(srcA[j] + (size_t)kt * KT64_B, lds + buf * KT64_B + dstA[j]);
    #pragma unroll
    for (int j = 0; j < 3; ++j)
      gl2lds(srcB[j] + (size_t)kt * 256, ldsB + buf * BBUF + dstB[j]);
  };

  f32x4 acc[5][3];
  #pragma unroll
  for (int fm = 0; fm < 5; ++fm)
    #pragma unroll
    for (int fn = 0; fn < 3; ++fn)
      acc[fm][fn] = f32x4{0.f, 0.f, 0.f, 0.f};

  auto COMP = [&](int buf) {
    const char* aT = lds + buf * KT64_B;
    const char* bT = ldsB + buf * BBUF;
    #pragma unroll
    for (int s = 0; s < 2; ++s) {
      const char* aB = aT + (s * 4 + kq) * PLANE_B + (wm * 80 + l15) * 16;
      bf16x8 af[5], bf[3];
      #pragma unroll
      for (int fm = 0; fm < 5; ++fm) af[fm] = *(const bf16x8*)(aB + fm * 256);
      #pragma unroll
      for (int fn = 0; fn < 3; ++fn) {
        int col = wn * 48 + fn * 16 + l15;
        int slot = ((s * 4 + kq) ^ (col & 7)) << 5;
        const char* cp = bT + col * 256 + slot;
        float4 lo = *(const float4*)cp;
        float4 hi = *(const float4*)(cp + 16);
        union { bf16x8 v; unsigned u[4]; } r;
        r.u[0] = cvt2bf(lo.x, lo.y); r.u[1] = cvt2bf(lo.z, lo.w);
        r.u[2] = cvt2bf(hi.x, hi.y); r.u[3] = cvt2bf(hi.z, hi.w);
        bf[fn] = r.v;
      }
      #pragma unroll
      for (int fm = 0; fm < 5; ++fm)
        #pragma unroll
        for (int fn = 0; fn < 3; ++fn)
          acc[fm][fn] = __builtin_amdgcn_mfma_f32_16x16x32_bf16(af[fm], bf[fn], acc[fm][fn], 0, 0, 0);
    }
  };

  STAGE(0, 0);
  for (int kt = 0; kt < NKT64; ++kt) {
    if (kt + 1 < NKT64) {
      STAGE(kt + 1, (kt + 1) & 1);
      if (V == 5) { WAITVM(8) } else { WAITVM(7) }
    } else { WAITVM(0) }
    barrier();
    COMP(kt & 1);
    barrier();
  }

  const int base = meta[8 + e];
  #pragma unroll
  for (int fm = 0; fm < 5; ++fm) {
    #pragma unroll
    for (int j = 0; j < 4; ++j) {
      int rin = wm * 80 + fm * 16 + kq * 4 + j;
      int aidx = (rin < rows) ? list[base + m0 + rin] : -1;
      #pragma unroll
      for (int fn = 0; fn < 3; ++fn) {
        int col = nt * BN_ + wn * 48 + fn * 16 + l15;
        if (aidx >= 0)
          out[(size_t)aidx * HIDDEN + col] = acc[fm][fn][j] + dbias[e * HIDDEN + col];
      }
    }
  }
}

extern "C" void kernel_launch(void* const* d_in, const int* in_sizes, int n_in,
                              void* d_out, int out_size, void* d_ws, size_t ws_size,
                              hipStream_t stream) {
  const float* t     = (const float*)d_in[0];
  const int*   eidx  = (const int*)d_in[1];
  const float* gup   = (const float*)d_in[2];
  const float* gub   = (const float*)d_in[3];
  const float* dwn   = (const float*)d_in[4];
  const float* dbias = (const float*)d_in[5];
  float* out = (float*)d_out;

  char* ws = (char*)d_ws;
  char* atile = ws;
  char* utile = ws + IMG_BYTES;
  int* meta = (int*)(ws + 2 * IMG_BYTES);
  int* list = meta + 32;

  route_count<<<1, 256, 0, stream>>>(eidx, meta);
  route_scatter<<<NPAIR / 256, 256, 0, stream>>>(eidx, meta, list);
  gather_a<<<NPAIR, 256, 0, stream>>>(t, eidx, meta, list, atile);

  dim3 g1(NEXP, GUP_ROWS / 64, 2);    // 8 x 90 x 2 (mt=1 safety tier, normally exits)
  gemm1_swiglu<<<g1, 256, 0, stream>>>(atile, gup, gub, meta, utile);

  dim3 g2(NEXP, HIDDEN / 96, 2);      // 8 x 30 x 2
  gemm2_down<<<g2, 512, 0, stream>>>(utile, dwn, dbias, meta, list, out);
}

// Round 17
// 318.463 us; speedup vs baseline: 1.0267x; 1.0267x over previous
//
#include <hip/hip_runtime.h>
#include <hip/hip_bf16.h>

#define HIDDEN   2880
#define INTER    2880
#define NEXP     8
#define GUP_ROWS 5760
#define NPAIR    2048

#define BM    320
#define PLANE_B 5120         // one 8-k plane: 320 rows x 16B
#define KT64_B  40960
#define NKT64   45
#define KT32_B  20480        // BK=32 tile: 4 planes
#define NKT32   90

#define MAXTILES 15
#define IMG_BYTES ((size_t)MAXTILES * NKT64 * KT64_B)

using bf16x8 = __attribute__((ext_vector_type(8))) short;
using f32x4  = __attribute__((ext_vector_type(4))) float;

typedef const __attribute__((address_space(1))) unsigned GBuf;
typedef __attribute__((address_space(3))) unsigned LBuf;

__device__ __forceinline__ void gl2lds(const void* g, void* l) {
  __builtin_amdgcn_global_load_lds((GBuf*)g, (LBuf*)l, 16, 0, 0);
}
#define WAITVM(N) { asm volatile("s_waitcnt vmcnt(" #N ")" ::: "memory"); \
                    __builtin_amdgcn_sched_barrier(0); }
__device__ __forceinline__ void barrier() {
  __builtin_amdgcn_sched_barrier(0);
  __builtin_amdgcn_s_barrier();
  __builtin_amdgcn_sched_barrier(0);
}

__device__ __forceinline__ unsigned cvt2bf(float a, float b) {
  union { __hip_bfloat16 h; unsigned short s; } x, y;
  x.h = __float2bfloat16(a);
  y.h = __float2bfloat16(b);
  return (unsigned)x.s | ((unsigned)y.s << 16);
}
__device__ __forceinline__ bf16x8 cvt8(const float4& lo, const float4& hi) {
  union { bf16x8 v; unsigned u[4]; } r;
  r.u[0] = cvt2bf(lo.x, lo.y);
  r.u[1] = cvt2bf(lo.z, lo.w);
  r.u[2] = cvt2bf(hi.x, hi.y);
  r.u[3] = cvt2bf(hi.z, hi.w);
  return r.v;
}

// ---------------- routing ----------------
__global__ void route_count(const int* __restrict__ eidx, int* __restrict__ meta) {
  __shared__ int cnt[NEXP];
  int t = threadIdx.x;
  if (t < NEXP) cnt[t] = 0;
  __syncthreads();
  for (int a = t; a < NPAIR; a += 256) atomicAdd(&cnt[eidx[a]], 1);
  __syncthreads();
  if (t == 0) {
    int off = 0, toff = 0;
    for (int e = 0; e < NEXP; ++e) {
      meta[e] = cnt[e];
      meta[8 + e] = off;
      meta[16 + e] = off;
      meta[24 + e] = toff;
      off += cnt[e];
      toff += (cnt[e] + BM - 1) / BM;
    }
  }
}

__global__ void route_scatter(const int* __restrict__ eidx, int* __restrict__ meta,
                              int* __restrict__ list) {
  int a = blockIdx.x * 256 + threadIdx.x;
  int e = eidx[a];
  int pos = atomicAdd(&meta[16 + e], 1);
  list[pos] = a;
}

// ---------------- gather A rows -> bf16 tiled fragment image ----------------
// layout: [tile][k>>3 plane 0..359][row 0..319][16B]
__global__ void gather_a(const float* __restrict__ t, const int* __restrict__ eidx,
                         const int* __restrict__ meta, const int* __restrict__ list,
                         char* __restrict__ atile) {
  const int i = blockIdx.x;
  const int a = list[i];
  const int e = eidx[a];
  const int r = i - meta[8 + e];
  const int tile = meta[24 + e] + r / BM;
  const int row = r % BM;
  const float* src = t + (size_t)(a >> 2) * HIDDEN;
  for (int ch = threadIdx.x; ch < HIDDEN / 8; ch += 256) {
    const float4* s = (const float4*)(src + ch * 8);
    float4 v0 = s[0], v1 = s[1];
    uint4 w;
    w.x = cvt2bf(v0.x, v0.y); w.y = cvt2bf(v0.z, v0.w);
    w.z = cvt2bf(v1.x, v1.y); w.w = cvt2bf(v1.z, v1.w);
    *(uint4*)(atile + ((size_t)tile * 360 + ch) * PLANE_B + row * 16) = w;
  }
}

// ---------------- GEMM1 (R14 verbatim): 4 waves, tile 320x96, BK=32, 64KB LDS -> 2 blocks/CU ----------------
__global__ __launch_bounds__(256, 2)
void gemm1_swiglu(const char* __restrict__ aimg,
                  const float* __restrict__ gup,
                  const float* __restrict__ gub,
                  const int* __restrict__ meta,
                  char* __restrict__ uimg)
{
  const int e = blockIdx.x, nt = blockIdx.y, mt = blockIdx.z;
  const int n_e = meta[e];
  const int m0 = mt * BM;
  if (m0 >= n_e) return;
  const int tile = meta[24 + e] + mt;
  int rows = n_e - m0; if (rows > BM) rows = BM;

  __shared__ __align__(16) char lds[2 * 32768];   // 64 KB

  const int tid = threadIdx.x, lane = tid & 63, wid = tid >> 6;
  const int wm = wid;
  const int kq = lane >> 4, l15 = lane & 15;

  const char* aSrc = aimg + (size_t)tile * 360 * PLANE_B;
  const char* srcA[5]; int dstA[5];
  #pragma unroll
  for (int j = 0; j < 5; ++j) {
    int c = wid * 5 + j;
    srcA[j] = aSrc + c * 1024 + lane * 16;
    dstA[j] = c * 1024;
  }
  const char* srcB[3]; int dstB[3];
  #pragma unroll
  for (int j = 0; j < 3; ++j) {
    int cb = wid * 3 + j;
    int col = nt * 96 + cb * 8 + (lane >> 3);
    int g = (lane & 7) >> 1, h = lane & 1;
    srcB[j] = (const char*)gup + (size_t)(e * GUP_ROWS + col) * (HIDDEN * 4)
              + (((g ^ (col & 3)) << 5) | (h << 4));
    dstB[j] = 20480 + cb * 1024;
  }

  auto STAGE = [&](int kt, int buf) {
    char* dst = lds + buf * 32768;
    #pragma unroll
    for (int j = 0; j < 5; ++j)
      gl2lds(srcA[j] + (size_t)kt * KT32_B, dst + dstA[j]);
    #pragma unroll
    for (int j = 0; j < 3; ++j)
      gl2lds(srcB[j] + (size_t)kt * 128, dst + dstB[j]);
  };

  f32x4 acc[5][6];
  #pragma unroll
  for (int fm = 0; fm < 5; ++fm)
    #pragma unroll
    for (int fn = 0; fn < 6; ++fn)
      acc[fm][fn] = f32x4{0.f, 0.f, 0.f, 0.f};

  auto COMP = [&](int buf) {
    const char* base = lds + buf * 32768;
    const char* aB = base + kq * PLANE_B + (wm * 80 + l15) * 16;
    bf16x8 af[5], bf[6];
    #pragma unroll
    for (int fm = 0; fm < 5; ++fm) af[fm] = *(const bf16x8*)(aB + fm * 256);
    #pragma unroll
    for (int fn = 0; fn < 6; ++fn) {
      int col = fn * 16 + l15;
      const char* cp = base + 20480 + col * 128 + ((kq ^ (col & 3)) << 5);
      float4 lo = *(const float4*)cp;
      float4 hi = *(const float4*)(cp + 16);
      bf[fn] = cvt8(lo, hi);
    }
    #pragma unroll
    for (int fm = 0; fm < 5; ++fm)
      #pragma unroll
      for (int fn = 0; fn < 6; ++fn)
        acc[fm][fn] = __builtin_amdgcn_mfma_f32_16x16x32_bf16(af[fm], bf[fn], acc[fm][fn], 0, 0, 0);
  };

  STAGE(0, 0);
  for (int kt = 0; kt < NKT32; ++kt) {
    if (kt + 1 < NKT32) {
      STAGE(kt + 1, (kt + 1) & 1);
      WAITVM(8)
    } else { WAITVM(0) }
    barrier();
    COMP(kt & 1);
    barrier();
  }

  #pragma unroll
  for (int fm = 0; fm < 5; ++fm) {
    #pragma unroll
    for (int fn = 0; fn < 6; ++fn) {
      const int colg = nt * 96 + fn * 16 + l15;
      const float bias = gub[e * GUP_ROWS + colg];
      #pragma unroll
      for (int j = 0; j < 4; ++j) {
        float h = acc[fm][fn][j] + bias;
        float other = __shfl_xor(h, 1, 64);
        int rowin = wm * 80 + fm * 16 + kq * 4 + j;
        if (!(lane & 1) && rowin < rows) {
          float xg = fminf(h, 7.0f);
          float xl = fminf(fmaxf(other, -7.0f), 7.0f);
          float og = xg / (1.0f + __expf(-1.702f * xg));
          float uv = og * (xl + 1.0f);
          int uc = colg >> 1;                      // 0..2879
          *(__hip_bfloat16*)(uimg + ((size_t)tile * 360 + (uc >> 3)) * PLANE_B +
              rowin * 16 + (uc & 7) * 2) = __float2bfloat16(uv);
        }
      }
    }
  }
}

// ---------------- GEMM2: same 4-wave template, tile 320x64, BK=32, 57KB LDS -> 2 blocks/CU ----------------
// 28 chunks/iter (20 A + 8 B), 7 gl2lds/wave -> WAITVM(7). Grid 8 x 45 -> 360 blocks (2-stream).
__global__ __launch_bounds__(256, 2)
void gemm2_down(const char* __restrict__ uimg,
                const float* __restrict__ dwn,
                const float* __restrict__ dbias,
                const int* __restrict__ meta,
                const int* __restrict__ list,
                float* __restrict__ out)
{
  const int e = blockIdx.x, nt = blockIdx.y, mt = blockIdx.z;
  const int n_e = meta[e];
  const int m0 = mt * BM;
  if (m0 >= n_e) return;
  const int tile = meta[24 + e] + mt;
  int rows = n_e - m0; if (rows > BM) rows = BM;

  __shared__ __align__(16) char lds[2 * 20480 + 2 * 8192];   // 57344
  char* ldsB = lds + 2 * 20480;

  const int tid = threadIdx.x, lane = tid & 63, wid = tid >> 6;
  const int wm = wid;
  const int kq = lane >> 4, l15 = lane & 15;

  const char* aSrc = uimg + (size_t)tile * 360 * PLANE_B;
  const char* srcA[5]; int dstA[5];
  #pragma unroll
  for (int j = 0; j < 5; ++j) {
    int c = wid * 5 + j;
    srcA[j] = aSrc + c * 1024 + lane * 16;
    dstA[j] = c * 1024;
  }
  const char* srcB[2]; int dstB[2];
  #pragma unroll
  for (int j = 0; j < 2; ++j) {
    int cb = wid * 2 + j;
    int col = nt * 64 + cb * 8 + (lane >> 3);
    int g = (lane & 7) >> 1, h = lane & 1;
    srcB[j] = (const char*)dwn + (size_t)(e * HIDDEN + col) * (INTER * 4)
              + (((g ^ (col & 3)) << 5) | (h << 4));
    dstB[j] = cb * 1024;
  }

  auto STAGE = [&](int kt, int buf) {
    #pragma unroll
    for (int j = 0; j < 5; ++j)
      gl2lds(srcA[j] + (size_t)kt * KT32_B, lds + buf * 20480 + dstA[j]);
    #pragma unroll
    for (int j = 0; j < 2; ++j)
      gl2lds(srcB[j] + (size_t)kt * 128, ldsB + buf * 8192 + dstB[j]);
  };

  f32x4 acc[5][4];
  #pragma unroll
  for (int fm = 0; fm < 5; ++fm)
    #pragma unroll
    for (int fn = 0; fn < 4; ++fn)
      acc[fm][fn] = f32x4{0.f, 0.f, 0.f, 0.f};

  auto COMP = [&](int buf) {
    const char* aB = lds + buf * 20480 + kq * PLANE_B + (wm * 80 + l15) * 16;
    const char* bT = ldsB + buf * 8192;
    bf16x8 af[5], bf[4];
    #pragma unroll
    for (int fm = 0; fm < 5; ++fm) af[fm] = *(const bf16x8*)(aB + fm * 256);
    #pragma unroll
    for (int fn = 0; fn < 4; ++fn) {
      int col = fn * 16 + l15;
      const char* cp = bT + col * 128 + ((kq ^ (col & 3)) << 5);
      float4 lo = *(const float4*)cp;
      float4 hi = *(const float4*)(cp + 16);
      bf[fn] = cvt8(lo, hi);
    }
    #pragma unroll
    for (int fm = 0; fm < 5; ++fm)
      #pragma unroll
      for (int fn = 0; fn < 4; ++fn)
        acc[fm][fn] = __builtin_amdgcn_mfma_f32_16x16x32_bf16(af[fm], bf[fn], acc[fm][fn], 0, 0, 0);
  };

  STAGE(0, 0);
  for (int kt = 0; kt < NKT32; ++kt) {
    if (kt + 1 < NKT32) {
      STAGE(kt + 1, (kt + 1) & 1);
      WAITVM(7)
    } else { WAITVM(0) }
    barrier();
    COMP(kt & 1);
    barrier();
  }

  const int base = meta[8 + e];
  #pragma unroll
  for (int fm = 0; fm < 5; ++fm) {
    #pragma unroll
    for (int j = 0; j < 4; ++j) {
      int rin = wm * 80 + fm * 16 + kq * 4 + j;
      int aidx = (rin < rows) ? list[base + m0 + rin] : -1;
      #pragma unroll
      for (int fn = 0; fn < 4; ++fn) {
        int col = nt * 64 + fn * 16 + l15;
        if (aidx >= 0)
          out[(size_t)aidx * HIDDEN + col] = acc[fm][fn][j] + dbias[e * HIDDEN + col];
      }
    }
  }
}

extern "C" void kernel_launch(void* const* d_in, const int* in_sizes, int n_in,
                              void* d_out, int out_size, void* d_ws, size_t ws_size,
                              hipStream_t stream) {
  const float* t     = (const float*)d_in[0];
  const int*   eidx  = (const int*)d_in[1];
  const float* gup   = (const float*)d_in[2];
  const float* gub   = (const float*)d_in[3];
  const float* dwn   = (const float*)d_in[4];
  const float* dbias = (const float*)d_in[5];
  float* out = (float*)d_out;

  char* ws = (char*)d_ws;
  char* atile = ws;
  char* utile = ws + IMG_BYTES;
  int* meta = (int*)(ws + 2 * IMG_BYTES);
  int* list = meta + 32;

  route_count<<<1, 256, 0, stream>>>(eidx, meta);
  route_scatter<<<NPAIR / 256, 256, 0, stream>>>(eidx, meta, list);
  gather_a<<<NPAIR, 256, 0, stream>>>(t, eidx, meta, list, atile);

  dim3 g1(NEXP, GUP_ROWS / 96, 2);    // 8 x 60 x 2 (mt=1 safety tier, normally exits)
  gemm1_swiglu<<<g1, 256, 0, stream>>>(atile, gup, gub, meta, utile);

  dim3 g2(NEXP, HIDDEN / 64, 2);      // 8 x 45 x 2 -> 360+ blocks, 2 streams/CU
  gemm2_down<<<g2, 256, 0, stream>>>(utile, dwn, dbias, meta, list, out);
}

// Round 18
// 299.211 us; speedup vs baseline: 1.0928x; 1.0643x over previous
//
#include <hip/hip_runtime.h>
#include <hip/hip_bf16.h>

#define HIDDEN   2880
#define INTER    2880
#define NEXP     8
#define GUP_ROWS 5760
#define NPAIR    2048

#define BM    320
#define PLANE_B 5120         // one 8-k plane: 320 rows x 16B
#define KT64_B  40960        // BK=64 tile: 8 planes
#define NKT64   45
#define KT32_B  20480        // BK=32 tile: 4 planes
#define NKT32   90

#define MAXTILES 15
#define IMG_BYTES ((size_t)MAXTILES * NKT64 * KT64_B)

using bf16x8 = __attribute__((ext_vector_type(8))) short;
using f32x4  = __attribute__((ext_vector_type(4))) float;

typedef const __attribute__((address_space(1))) unsigned GBuf;
typedef __attribute__((address_space(3))) unsigned LBuf;

__device__ __forceinline__ void gl2lds(const void* g, void* l) {
  __builtin_amdgcn_global_load_lds((GBuf*)g, (LBuf*)l, 16, 0, 0);
}
#define WAITVM(N) { asm volatile("s_waitcnt vmcnt(" #N ")" ::: "memory"); \
                    __builtin_amdgcn_sched_barrier(0); }
__device__ __forceinline__ void barrier() {
  __builtin_amdgcn_sched_barrier(0);
  __builtin_amdgcn_s_barrier();
  __builtin_amdgcn_sched_barrier(0);
}

__device__ __forceinline__ unsigned cvt2bf(float a, float b) {
  union { __hip_bfloat16 h; unsigned short s; } x, y;
  x.h = __float2bfloat16(a);
  y.h = __float2bfloat16(b);
  return (unsigned)x.s | ((unsigned)y.s << 16);
}
__device__ __forceinline__ bf16x8 cvt8(const float4& lo, const float4& hi) {
  union { bf16x8 v; unsigned u[4]; } r;
  r.u[0] = cvt2bf(lo.x, lo.y);
  r.u[1] = cvt2bf(lo.z, lo.w);
  r.u[2] = cvt2bf(hi.x, hi.y);
  r.u[3] = cvt2bf(hi.z, hi.w);
  return r.v;
}

// ---------------- routing ----------------
__global__ void route_count(const int* __restrict__ eidx, int* __restrict__ meta) {
  __shared__ int cnt[NEXP];
  int t = threadIdx.x;
  if (t < NEXP) cnt[t] = 0;
  __syncthreads();
  for (int a = t; a < NPAIR; a += 256) atomicAdd(&cnt[eidx[a]], 1);
  __syncthreads();
  if (t == 0) {
    int off = 0, toff = 0;
    for (int e = 0; e < NEXP; ++e) {
      meta[e] = cnt[e];
      meta[8 + e] = off;
      meta[16 + e] = off;
      meta[24 + e] = toff;
      off += cnt[e];
      toff += (cnt[e] + BM - 1) / BM;
    }
  }
}

__global__ void route_scatter(const int* __restrict__ eidx, int* __restrict__ meta,
                              int* __restrict__ list) {
  int a = blockIdx.x * 256 + threadIdx.x;
  int e = eidx[a];
  int pos = atomicAdd(&meta[16 + e], 1);
  list[pos] = a;
}

// ---------------- gather A rows -> bf16 tiled fragment image ----------------
// layout: [tile][k>>3 plane 0..359][row 0..319][16B]
__global__ void gather_a(const float* __restrict__ t, const int* __restrict__ eidx,
                         const int* __restrict__ meta, const int* __restrict__ list,
                         char* __restrict__ atile) {
  const int i = blockIdx.x;
  const int a = list[i];
  const int e = eidx[a];
  const int r = i - meta[8 + e];
  const int tile = meta[24 + e] + r / BM;
  const int row = r % BM;
  const float* src = t + (size_t)(a >> 2) * HIDDEN;
  for (int ch = threadIdx.x; ch < HIDDEN / 8; ch += 256) {
    const float4* s = (const float4*)(src + ch * 8);
    float4 v0 = s[0], v1 = s[1];
    uint4 w;
    w.x = cvt2bf(v0.x, v0.y); w.y = cvt2bf(v0.z, v0.w);
    w.z = cvt2bf(v1.x, v1.y); w.w = cvt2bf(v1.z, v1.w);
    *(uint4*)(atile + ((size_t)tile * 360 + ch) * PLANE_B + row * 16) = w;
  }
}

// ---------------- GEMM1: 4 waves, tile 320x96, BK=32, 64KB LDS -> 2 blocks/CU ----------------
// 32 chunks/iter (20 A + 12 B), 8 gl2lds/wave -> WAITVM(8).
__global__ __launch_bounds__(256, 2)
void gemm1_swiglu(const char* __restrict__ aimg,
                  const float* __restrict__ gup,
                  const float* __restrict__ gub,
                  const int* __restrict__ meta,
                  char* __restrict__ uimg)
{
  const int e = blockIdx.x, nt = blockIdx.y, mt = blockIdx.z;
  const int n_e = meta[e];
  const int m0 = mt * BM;
  if (m0 >= n_e) return;
  const int tile = meta[24 + e] + mt;
  int rows = n_e - m0; if (rows > BM) rows = BM;

  __shared__ __align__(16) char lds[2 * 32768];   // 64 KB

  const int tid = threadIdx.x, lane = tid & 63, wid = tid >> 6;
  const int wm = wid;
  const int kq = lane >> 4, l15 = lane & 15;

  const char* aSrc = aimg + (size_t)tile * 360 * PLANE_B;
  // A: 20 chunks of 1KB, 5 per wave
  const char* srcA[5]; int dstA[5];
  #pragma unroll
  for (int j = 0; j < 5; ++j) {
    int c = wid * 5 + j;
    srcA[j] = aSrc + c * 1024 + lane * 16;
    dstA[j] = c * 1024;
  }
  // B: 12 chunks of 1KB (8 cols x 128B), 3 per wave; swizzle in SOURCE addr
  const char* srcB[3]; int dstB[3];
  #pragma unroll
  for (int j = 0; j < 3; ++j) {
    int cb = wid * 3 + j;
    int col = nt * 96 + cb * 8 + (lane >> 3);
    int g = (lane & 7) >> 1, h = lane & 1;
    srcB[j] = (const char*)gup + (size_t)(e * GUP_ROWS + col) * (HIDDEN * 4)
              + (((g ^ (col & 3)) << 5) | (h << 4));
    dstB[j] = 20480 + cb * 1024;
  }

  auto STAGE = [&](int kt, int buf) {
    char* dst = lds + buf * 32768;
    #pragma unroll
    for (int j = 0; j < 5; ++j)
      gl2lds(srcA[j] + (size_t)kt * KT32_B, dst + dstA[j]);
    #pragma unroll
    for (int j = 0; j < 3; ++j)
      gl2lds(srcB[j] + (size_t)kt * 128, dst + dstB[j]);
  };

  f32x4 acc[5][6];
  #pragma unroll
  for (int fm = 0; fm < 5; ++fm)
    #pragma unroll
    for (int fn = 0; fn < 6; ++fn)
      acc[fm][fn] = f32x4{0.f, 0.f, 0.f, 0.f};

  auto COMP = [&](int buf) {
    const char* base = lds + buf * 32768;
    const char* aB = base + kq * PLANE_B + (wm * 80 + l15) * 16;
    bf16x8 af[5], bf[6];
    #pragma unroll
    for (int fm = 0; fm < 5; ++fm) af[fm] = *(const bf16x8*)(aB + fm * 256);
    #pragma unroll
    for (int fn = 0; fn < 6; ++fn) {
      int col = fn * 16 + l15;
      const char* cp = base + 20480 + col * 128 + ((kq ^ (col & 3)) << 5);
      float4 lo = *(const float4*)cp;
      float4 hi = *(const float4*)(cp + 16);
      bf[fn] = cvt8(lo, hi);
    }
    #pragma unroll
    for (int fm = 0; fm < 5; ++fm)
      #pragma unroll
      for (int fn = 0; fn < 6; ++fn)
        acc[fm][fn] = __builtin_amdgcn_mfma_f32_16x16x32_bf16(af[fm], bf[fn], acc[fm][fn], 0, 0, 0);
  };

  STAGE(0, 0);
  for (int kt = 0; kt < NKT32; ++kt) {
    if (kt + 1 < NKT32) {
      STAGE(kt + 1, (kt + 1) & 1);
      WAITVM(8)
    } else { WAITVM(0) }
    barrier();
    COMP(kt & 1);
    barrier();
  }

  // epilogue: +bias, swiglu (even col = glu, odd = lin), write u into uimg
  #pragma unroll
  for (int fm = 0; fm < 5; ++fm) {
    #pragma unroll
    for (int fn = 0; fn < 6; ++fn) {
      const int colg = nt * 96 + fn * 16 + l15;
      const float bias = gub[e * GUP_ROWS + colg];
      #pragma unroll
      for (int j = 0; j < 4; ++j) {
        float h = acc[fm][fn][j] + bias;
        float other = __shfl_xor(h, 1, 64);
        int rowin = wm * 80 + fm * 16 + kq * 4 + j;
        if (!(lane & 1) && rowin < rows) {
          float xg = fminf(h, 7.0f);
          float xl = fminf(fmaxf(other, -7.0f), 7.0f);
          float og = xg / (1.0f + __expf(-1.702f * xg));
          float uv = og * (xl + 1.0f);
          int uc = colg >> 1;                      // 0..2879
          *(__hip_bfloat16*)(uimg + ((size_t)tile * 360 + (uc >> 3)) * PLANE_B +
              rowin * 16 + (uc & 7) * 2) = __float2bfloat16(uv);
        }
      }
    }
  }
}

// ---------------- GEMM2: 8 waves (4 wm x 2 wn), tile 320x96, BK=64 ----------------
__global__ __launch_bounds__(512, 1)
void gemm2_down(const char* __restrict__ uimg,
                const float* __restrict__ dwn,
                const float* __restrict__ dbias,
                const int* __restrict__ meta,
                const int* __restrict__ list,
                float* __restrict__ out)
{
  constexpr int BN_ = 96;
  constexpr int BBUF = BN_ * 256;       // 24576

  const int e = blockIdx.x, nt = blockIdx.y, mt = blockIdx.z;
  const int n_e = meta[e];
  const int m0 = mt * BM;
  if (m0 >= n_e) return;
  const int tile = meta[24 + e] + mt;
  int rows = n_e - m0; if (rows > BM) rows = BM;

  __shared__ __align__(16) char lds[2 * KT64_B + 2 * BBUF];   // 128 KB
  char* ldsB = lds + 2 * KT64_B;

  const int tid = threadIdx.x, lane = tid & 63, wid = tid >> 6;
  const int wm = wid >> 1, wn = wid & 1;
  const int kq = lane >> 4, l15 = lane & 15;

  const char* aSrcBase = uimg + (size_t)tile * 360 * PLANE_B;
  const char* srcA[5]; int dstA[5];
  #pragma unroll
  for (int j = 0; j < 5; ++j) {
    srcA[j] = aSrcBase + wid * PLANE_B + j * 1024 + lane * 16;
    dstA[j] = wid * PLANE_B + j * 1024;
  }
  const char* srcB[3]; int dstB[3];
  #pragma unroll
  for (int j = 0; j < 3; ++j) {
    int cb = wid * 3 + j;
    int col = nt * BN_ + cb * 4 + (lane >> 4);
    int s16 = lane & 15;
    int swz = (((s16 >> 1) ^ (col & 7)) << 5) | ((s16 & 1) << 4);
    srcB[j] = (const char*)dwn + ((size_t)(e * HIDDEN + col) * INTER) * 4 + swz;
    dstB[j] = cb * 1024;
  }

  auto STAGE = [&](int kt, int buf) {
    #pragma unroll
    for (int j = 0; j < 5; ++j)
      gl2lds(srcA[j] + (size_t)kt * KT64_B, lds + buf * KT64_B + dstA[j]);
    #pragma unroll
    for (int j = 0; j < 3; ++j)
      gl2lds(srcB[j] + (size_t)kt * 256, ldsB + buf * BBUF + dstB[j]);
  };

  f32x4 acc[5][3];
  #pragma unroll
  for (int fm = 0; fm < 5; ++fm)
    #pragma unroll
    for (int fn = 0; fn < 3; ++fn)
      acc[fm][fn] = f32x4{0.f, 0.f, 0.f, 0.f};

  auto COMP = [&](int buf) {
    const char* aT = lds + buf * KT64_B;
    const char* bT = ldsB + buf * BBUF;
    #pragma unroll
    for (int s = 0; s < 2; ++s) {
      const char* aB = aT + (s * 4 + kq) * PLANE_B + (wm * 80 + l15) * 16;
      bf16x8 af[5], bf[3];
      #pragma unroll
      for (int fm = 0; fm < 5; ++fm) af[fm] = *(const bf16x8*)(aB + fm * 256);
      #pragma unroll
      for (int fn = 0; fn < 3; ++fn) {
        int col = wn * 48 + fn * 16 + l15;
        int slot = ((s * 4 + kq) ^ (col & 7)) << 5;
        const char* cp = bT + col * 256 + slot;
        float4 lo = *(const float4*)cp;
        float4 hi = *(const float4*)(cp + 16);
        bf[fn] = cvt8(lo, hi);
      }
      #pragma unroll
      for (int fm = 0; fm < 5; ++fm)
        #pragma unroll
        for (int fn = 0; fn < 3; ++fn)
          acc[fm][fn] = __builtin_amdgcn_mfma_f32_16x16x32_bf16(af[fm], bf[fn], acc[fm][fn], 0, 0, 0);
    }
  };

  STAGE(0, 0);
  for (int kt = 0; kt < NKT64; ++kt) {
    if (kt + 1 < NKT64) {
      STAGE(kt + 1, (kt + 1) & 1);
      WAITVM(8)
    } else { WAITVM(0) }
    barrier();
    COMP(kt & 1);
    barrier();
  }

  const int base = meta[8 + e];
  #pragma unroll
  for (int fm = 0; fm < 5; ++fm) {
    #pragma unroll
    for (int j = 0; j < 4; ++j) {
      int rin = wm * 80 + fm * 16 + kq * 4 + j;
      int aidx = (rin < rows) ? list[base + m0 + rin] : -1;
      #pragma unroll
      for (int fn = 0; fn < 3; ++fn) {
        int col = nt * BN_ + wn * 48 + fn * 16 + l15;
        if (aidx >= 0)
          out[(size_t)aidx * HIDDEN + col] = acc[fm][fn][j] + dbias[e * HIDDEN + col];
      }
    }
  }
}

extern "C" void kernel_launch(void* const* d_in, const int* in_sizes, int n_in,
                              void* d_out, int out_size, void* d_ws, size_t ws_size,
                              hipStream_t stream) {
  const float* t     = (const float*)d_in[0];
  const int*   eidx  = (const int*)d_in[1];
  const float* gup   = (const float*)d_in[2];
  const float* gub   = (const float*)d_in[3];
  const float* dwn   = (const float*)d_in[4];
  const float* dbias = (const float*)d_in[5];
  float* out = (float*)d_out;

  char* ws = (char*)d_ws;
  char* atile = ws;
  char* utile = ws + IMG_BYTES;
  int* meta = (int*)(ws + 2 * IMG_BYTES);
  int* list = meta + 32;

  route_count<<<1, 256, 0, stream>>>(eidx, meta);
  route_scatter<<<NPAIR / 256, 256, 0, stream>>>(eidx, meta, list);
  gather_a<<<NPAIR, 256, 0, stream>>>(t, eidx, meta, list, atile);

  dim3 g1(NEXP, GUP_ROWS / 96, 2);    // 8 x 60 x 2 (mt=1 safety tier, normally exits)
  gemm1_swiglu<<<g1, 256, 0, stream>>>(atile, gup, gub, meta, utile);

  dim3 g2(NEXP, HIDDEN / 96, 2);      // 8 x 30 x 2
  gemm2_down<<<g2, 512, 0, stream>>>(utile, dwn, dbias, meta, list, out);
}